// Round 6
// baseline (205.795 us; speedup 1.0000x reference)
//
#include <hip/hip_runtime.h>

// ImportanceAggregator pipeline:
//   K0 convert_all  : feat fp32 -> featb bf16 (slice-major [8][NN][32] when
//                     slicemaj=1, row-major otherwise) and W -> wtp bf16.
//   K1 pool_sg      : XCD-sliced gather, v4. Slice-contiguous featb
//                     (3.2 MB/XCD < 4 MB L2) + blockIdx%8 -> XCD round-robin
//                     keeps each XCD's slice L2-resident: R5 PROVED it
//                     (FETCH 175 -> 37.5 MB). But v3 ran 62 us latency-bound:
//                     shfl(ds_bpermute)->addr->load chains, VGPR=36 => only
//                     ~4 gathers in flight. v4: NO cross-lane ops. Each
//                     8-lane group redundantly loads its node's full nbr/iw
//                     rows (group-uniform addrs -> HW broadcast, coalesced
//                     512 B spans), wsum = 15 VALU adds, gathers issued in
//                     two explicit 8-deep batches (>=8 in flight, R2).
//   K2 gemm_ln      : out = LN(agg @ W + b)*gamma + beta via MFMA 16x16x32,
//                     LDS-staged B double buffer (unchanged, proven).
// R4 LESSON (rigor): aggb scratch MUST NOT live in d_out (replay-poison race).
// aggb lives in d_ws (astr=256); d_out is write-only on the main path.
// Lessons pinned: no 64-thread blocks (R6); no hoisted runtime-indexed arrays
// (R4 alloca->LDS); float4 epilogue beats segment stores (R3 vs R5);
// launch_bounds min-waves is a VGPR cap -> spill (R7); natural alloc (R8);
// nt builtins need ext_vector types (R1); >=8 loads in flight per wave (R2);
// interleaved slices share 128 B lines -> thrash (R3); shfl in the address
// path serializes gathers (R5).
// Gates: pool_sg >= 56 us -> revert pool_b for good. convert/gemm >= 40 us
// in top-5 -> they are the next target ("rest" is ~129 us every round).

#define NN   50000
#define KNB  16
#define D    256
#define WSTR 272   // epilogue slab stride (floats): 272%32=16 -> 2-way alias = free

typedef __attribute__((ext_vector_type(8))) short short8;   // 8 x bf16 (4 VGPRs)
typedef __attribute__((ext_vector_type(4))) float f32x4;
typedef __attribute__((ext_vector_type(4))) unsigned short us4;  // nt-capable
typedef __attribute__((ext_vector_type(4))) int   i32x4;

static __device__ __forceinline__ unsigned short f2bf(float x) {
    unsigned int u = __float_as_uint(x);
    return (unsigned short)((u + 0x7FFFu + ((u >> 16) & 1u)) >> 16);  // RNE
}
static __device__ __forceinline__ float bf2f(unsigned short h) {
    return __uint_as_float((unsigned int)h << 16);
}

// ---------------- K0: both conversions in one dispatch --------------------
// blocks [0,nfb): feat fp32 -> featb bf16. slicemaj=1: slice-major, addr =
//   s*(NN*32) + n*32 + d  (slice s = dims [s*32,s*32+32) of all rows, one
//   contiguous 3.2 MB block). slicemaj=0: row-major (R0 layout).
// blocks [nfb,nfb+32): W -> bf16 packed kb-major: frag g=(kb*16+c)*64+lane
//   holds B[k = kb*32 + (lane>>4)*8 + j][n = c*16 + (lane&15)].
__global__ __launch_bounds__(256) void convert_all(const float* __restrict__ feat,
                                                   const float* __restrict__ Wm,
                                                   unsigned short* __restrict__ featb,
                                                   unsigned short* __restrict__ wtp,
                                                   int nfb, int slicemaj) {
    if ((int)blockIdx.x < nfb) {
        const size_t g = (size_t)blockIdx.x * 256 + threadIdx.x;
        const float4 a = *(const float4*)(feat + g * 8);
        const float4 b = *(const float4*)(feat + g * 8 + 4);
        short8 o;
        o[0] = (short)f2bf(a.x); o[1] = (short)f2bf(a.y);
        o[2] = (short)f2bf(a.z); o[3] = (short)f2bf(a.w);
        o[4] = (short)f2bf(b.x); o[5] = (short)f2bf(b.y);
        o[6] = (short)f2bf(b.z); o[7] = (short)f2bf(b.w);
        if (slicemaj) {
            const int n  = (int)(g >> 5);            // row
            const int s  = ((int)g >> 2) & 7;        // slice
            const int d0 = ((int)g & 3) * 8;         // dim offset within slice
            *(short8*)(featb + (size_t)s * ((size_t)NN * 32)
                             + (size_t)n * 32 + d0) = o;
        } else {
            *(short8*)(featb + g * 8) = o;
        }
    } else {
        const int g    = (blockIdx.x - nfb) * 256 + threadIdx.x;    // 0..8191
        const int lane = g & 63;
        const int c    = (g >> 6) & 15;
        const int kb   = g >> 10;
        const int n    = c * 16 + (lane & 15);
        const int k0   = kb * 32 + (lane >> 4) * 8;
        short8 v;
        #pragma unroll
        for (int j = 0; j < 8; ++j) v[j] = (short)f2bf(Wm[(size_t)(k0 + j) * D + n]);
        *(short8*)(wtp + (size_t)g * 8) = v;
    }
}

// ---------------- K1: XCD-sliced weighted neighbor pooling (v4) -----------
// Grid = 8 * ceil(NN/32); slice s = blockIdx&7 -> XCD s (round-robin).
// Wave = 8 nodes (nd = lane>>3) x 8 dim-quads (dl = lane&7). Per wave:
//   8 nt-loads (4 int4 + 4 float4): each 8-lane group reads its node's FULL
//     nbr/iw rows (uniform addr in group -> HW broadcast; per instr the wave
//     covers a coalesced 512 B span). All 16 (idx,w) land in registers.
//   wsum = 15 VALU adds (no shuffles anywhere).
//   2 batches x 8 independent 64 B gathers, then FMA (>=8 in flight).
//   1 x 8 B nt-store per lane -> agg row n dims [s*32+dl*4, +4).
__global__ __launch_bounds__(256) void pool_sg(
        const unsigned short* __restrict__ featb,   // [8][NN][32] slice-major
        const int*   __restrict__ nbr,
        const float* __restrict__ iw,
        unsigned short* __restrict__ aggb, int astr) {
    const int t     = threadIdx.x;
    const int lane  = t & 63;
    const int wq    = t >> 6;
    const int s     = blockIdx.x & 7;            // slice == XCD (heuristic only)
    const int chunk = blockIdx.x >> 3;
    const int nd    = lane >> 3;                 // node within wave 0..7
    const int dl    = lane & 7;                  // dim-quad within 64 B slice
    const int n     = chunk * 32 + wq * 8 + nd;
    const int nc    = min(n, NN - 1);            // clamp tail (stores guarded)
    const unsigned short* fs = featb + (size_t)s * ((size_t)NN * 32);

    // Full rows, redundant within each 8-lane group (uniform addr).
    const int*   nrow = nbr + (size_t)nc * KNB;
    const float* wrow = iw  + (size_t)nc * KNB;
    const i32x4 ia = __builtin_nontemporal_load((const i32x4*)(nrow));
    const i32x4 ib = __builtin_nontemporal_load((const i32x4*)(nrow + 4));
    const i32x4 ic = __builtin_nontemporal_load((const i32x4*)(nrow + 8));
    const i32x4 id = __builtin_nontemporal_load((const i32x4*)(nrow + 12));
    const f32x4 wa = __builtin_nontemporal_load((const f32x4*)(wrow));
    const f32x4 wb = __builtin_nontemporal_load((const f32x4*)(wrow + 4));
    const f32x4 wc = __builtin_nontemporal_load((const f32x4*)(wrow + 8));
    const f32x4 wd = __builtin_nontemporal_load((const f32x4*)(wrow + 12));

    const float ws = (wa[0] + wa[1] + wa[2] + wa[3])
                   + (wb[0] + wb[1] + wb[2] + wb[3])
                   + (wc[0] + wc[1] + wc[2] + wc[3])
                   + (wd[0] + wd[1] + wd[2] + wd[3]);
    const bool  zs  = (ws == 0.f);
    const float inv = zs ? (1.f / KNB) : (1.f / ws);

    float4 p = make_float4(0.f, 0.f, 0.f, 0.f);
#define LOADU(U, IV, E) \
    const us4 U = *(const us4*)(fs + (size_t)(unsigned)IV[E] * 32 + dl * 4)
#define ACCU(U, WV, E) { \
    const float wk_ = zs ? inv : (WV[E] * inv); \
    p.x += wk_ * bf2f(U[0]); p.y += wk_ * bf2f(U[1]); \
    p.z += wk_ * bf2f(U[2]); p.w += wk_ * bf2f(U[3]); }

    {   // batch 1: k = 0..7, all 8 loads issued before any use
        LOADU(u0, ia, 0); LOADU(u1, ia, 1); LOADU(u2, ia, 2); LOADU(u3, ia, 3);
        LOADU(u4, ib, 0); LOADU(u5, ib, 1); LOADU(u6, ib, 2); LOADU(u7, ib, 3);
        ACCU(u0, wa, 0); ACCU(u1, wa, 1); ACCU(u2, wa, 2); ACCU(u3, wa, 3);
        ACCU(u4, wb, 0); ACCU(u5, wb, 1); ACCU(u6, wb, 2); ACCU(u7, wb, 3);
    }
    {   // batch 2: k = 8..15
        LOADU(u8, ic, 0); LOADU(u9, ic, 1); LOADU(uA, ic, 2); LOADU(uB, ic, 3);
        LOADU(uC, id, 0); LOADU(uD, id, 1); LOADU(uE, id, 2); LOADU(uF, id, 3);
        ACCU(u8, wc, 0); ACCU(u9, wc, 1); ACCU(uA, wc, 2); ACCU(uB, wc, 3);
        ACCU(uC, wd, 0); ACCU(uD, wd, 1); ACCU(uE, wd, 2); ACCU(uF, wd, 3);
    }
#undef LOADU
#undef ACCU

    if (n < NN) {                                // agg row n, dims s*32+dl*4
        us4 o;
        o[0] = f2bf(p.x); o[1] = f2bf(p.y); o[2] = f2bf(p.z); o[3] = f2bf(p.w);
        __builtin_nontemporal_store(o,
            (us4*)(aggb + (size_t)n * astr + s * 32 + dl * 4));
    }
}

// ---------------- pool_b: proven R0 gather (row-major featb) --------------
__global__ __launch_bounds__(256, 8) void pool_b(const unsigned short* __restrict__ featb,
                                                 const int*   __restrict__ nbr,
                                                 const float* __restrict__ iw,
                                                 unsigned short* __restrict__ aggb,
                                                 int astr) {
    const int  t    = threadIdx.x;
    const int  lane = t & 63;
    const int  wq   = t >> 6;
    const long n    = (long)blockIdx.x * 4 + wq;   // one wave per node

    float ws = 0.f;
    #pragma unroll
    for (int k = 0; k < KNB; ++k) ws += iw[n * KNB + k];
    const bool  zs  = (ws == 0.f);
    const float inv = zs ? (1.f / KNB) : (1.f / ws);

    float4 p = make_float4(0.f, 0.f, 0.f, 0.f);
    #pragma unroll 1
    for (int kb = 0; kb < KNB; kb += 8) {          // 8 gathers in flight
        int   idx[8];
        float w[8];
        #pragma unroll
        for (int k = 0; k < 8; ++k) {
            idx[k] = nbr[n * KNB + kb + k];
            w[k]   = iw [n * KNB + kb + k];
        }
        #pragma unroll
        for (int k = 0; k < 8; ++k) {
            const float   wk = zs ? inv : (w[k] * inv);
            const ushort4 u  = *(const ushort4*)(featb + (size_t)idx[k] * D + lane * 4);
            p.x += wk * bf2f(u.x); p.y += wk * bf2f(u.y);
            p.z += wk * bf2f(u.z); p.w += wk * bf2f(u.w);
        }
    }
    ushort4 o;
    o.x = f2bf(p.x); o.y = f2bf(p.y); o.z = f2bf(p.z); o.w = f2bf(p.w);
    *(ushort4*)(aggb + (size_t)n * astr + lane * 4) = o;
}

// Fallback (ws too small for featb): fp32 gathers, one wave per node.
__global__ __launch_bounds__(256, 8) void pool_f(const float* __restrict__ feat,
                                                 const int*   __restrict__ nbr,
                                                 const float* __restrict__ iw,
                                                 unsigned short* __restrict__ aggb,
                                                 int astr) {
    const int  t    = threadIdx.x;
    const int  lane = t & 63;
    const int  wq   = t >> 6;
    const long n    = (long)blockIdx.x * 4 + wq;
    float ws = 0.f;
    #pragma unroll
    for (int k = 0; k < KNB; ++k) ws += iw[n * KNB + k];
    const bool  zs  = (ws == 0.f);
    const float inv = zs ? (1.f / KNB) : (1.f / ws);
    float4 p = make_float4(0.f, 0.f, 0.f, 0.f);
    #pragma unroll 1
    for (int kb = 0; kb < KNB; kb += 8) {
        int idx[8]; float w[8];
        #pragma unroll
        for (int k = 0; k < 8; ++k) { idx[k] = nbr[n*KNB+kb+k]; w[k] = iw[n*KNB+kb+k]; }
        #pragma unroll
        for (int k = 0; k < 8; ++k) {
            const float  wk = zs ? inv : (w[k] * inv);
            const float4 f  = *(const float4*)(feat + (size_t)idx[k] * D + lane * 4);
            p.x += wk*f.x; p.y += wk*f.y; p.z += wk*f.z; p.w += wk*f.w;
        }
    }
    ushort4 o;
    o.x = f2bf(p.x); o.y = f2bf(p.y); o.z = f2bf(p.z); o.w = f2bf(p.w);
    *(ushort4*)(aggb + (size_t)n * astr + lane * 4) = o;
}

// ---------------- K2: bf16 MFMA GEMM + LayerNorm, LDS-staged B ------------
// Block = 4 waves x 16 rows. B chunk (32 k x 256 n = 16 KB) double-buffered in
// LDS, shared by all 4 waves; one barrier per chunk. Staging hand-pipelined:
// global loads -> regs BEFORE the MFMA burst, ds_writes after, then barrier.
__global__ __launch_bounds__(256) void gemm_ln(const unsigned short* __restrict__ aggb,
                                               int astr,
                                               const unsigned short* __restrict__ wtp,
                                               const float* __restrict__ bias,
                                               const float* __restrict__ gamma,
                                               const float* __restrict__ beta,
                                               float* __restrict__ out) {
    __shared__ short sB[2][8192];                   // 2 x 16 KB B chunks
    __shared__ float fsh[4][4 * WSTR];              // 17.4 KB epilogue slabs

    const int t       = threadIdx.x;
    const int lane    = t & 63;
    const int wq      = t >> 6;
    const int quad    = lane >> 4;
    const int l15     = lane & 15;
    const int rowbase = blockIdx.x * 64 + wq * 16;

    const int arow = min(rowbase + l15, NN - 1);
    const unsigned short* aptr = aggb + (size_t)arow * astr + quad * 8;
    const short8* wv = (const short8*)wtp;          // frag u of chunk kb: wv[kb*1024+u]

    // Prefetch all 8 A-frags (independent 16 B loads, issued up front).
    short8 aF[8];
    #pragma unroll
    for (int kb = 0; kb < 8; ++kb) aF[kb] = *(const short8*)(aptr + kb * 32);

    // Stage chunk 0.
    #pragma unroll
    for (int i = 0; i < 4; ++i)
        *(short8*)&sB[0][(size_t)(i * 256 + t) * 8] = wv[i * 256 + t];
    __syncthreads();

    f32x4 acc[16];
    #pragma unroll
    for (int c = 0; c < 16; ++c) acc[c] = (f32x4){0.f, 0.f, 0.f, 0.f};

    #pragma unroll
    for (int kb = 0; kb < 8; ++kb) {
        const int buf = kb & 1;
        short8 stg[4];
        if (kb < 7) {                               // issue next-chunk loads now
            #pragma unroll
            for (int i = 0; i < 4; ++i)
                stg[i] = wv[(size_t)(kb + 1) * 1024 + i * 256 + t];
        }
        #pragma unroll
        for (int c = 0; c < 16; ++c) {              // conflict-free ds_read_b128
            const short8 b = *(const short8*)&sB[buf][(size_t)(c * 64 + lane) * 8];
            acc[c] = __builtin_amdgcn_mfma_f32_16x16x32_bf16(aF[kb], b, acc[c], 0, 0, 0);
        }
        if (kb < 7) {                               // park next chunk in other buffer
            #pragma unroll
            for (int i = 0; i < 4; ++i)
                *(short8*)&sB[buf ^ 1][(size_t)(i * 256 + t) * 8] = stg[i];
        }
        __syncthreads();                            // one barrier per chunk
    }

    // Epilogue: +bias, LN, per-wave transpose slab, gamma/beta after
    // transpose (col = lane*4 -> 2 hoisted float4s), coalesced float4 stores.
    float bv[16];
    #pragma unroll
    for (int c = 0; c < 16; ++c) bv[c] = bias[c * 16 + l15];
    const float4 gv4 = *(const float4*)(gamma + lane * 4);
    const float4 bt4 = *(const float4*)(beta  + lane * 4);
    float* wsh = fsh[wq];

    #pragma unroll
    for (int j = 0; j < 4; ++j) {       // C/D: row = quad*4 + j, col = c*16 + l15
        float s = 0.f, sq = 0.f;
        #pragma unroll
        for (int c = 0; c < 16; ++c) {
            const float v = acc[c][j] + bv[c];
            s += v; sq += v * v;
        }
        #pragma unroll
        for (int off = 1; off < 16; off <<= 1) {   // reduce across l15 (same quad)
            s  += __shfl_xor(s,  off, 64);
            sq += __shfl_xor(sq, off, 64);
        }
        const float mean = s * (1.f / D);
        const float var  = sq * (1.f / D) - mean * mean;   // biased (torch LN)
        const float rstd = rsqrtf(var + 1e-5f);
        #pragma unroll
        for (int c = 0; c < 16; ++c)               // row quad*4+j -> slab slot quad
            wsh[quad * WSTR + c * 16 + l15] = (acc[c][j] + bv[c] - mean) * rstd;
        // same-wave LDS dependency: compiler inserts lgkmcnt wait, no barrier
        #pragma unroll
        for (int p = 0; p < 4; ++p) {              // rows {j, 4+j, 8+j, 12+j}
            const long  r  = rowbase + p * 4 + j;
            if (r < NN) {
                const float4 v = *(const float4*)(wsh + p * WSTR + lane * 4);
                float4 o;
                o.x = v.x * gv4.x + bt4.x; o.y = v.y * gv4.y + bt4.y;
                o.z = v.z * gv4.z + bt4.z; o.w = v.w * gv4.w + bt4.w;
                *(float4*)(out + r * D + lane * 4) = o;   // coalesced 1 KB/instr
            }
        }
    }
}

extern "C" void kernel_launch(void* const* d_in, const int* in_sizes, int n_in,
                              void* d_out, int out_size, void* d_ws, size_t ws_size,
                              hipStream_t stream) {
    const float* feat = (const float*)d_in[0];
    const int*   nbr  = (const int*)d_in[1];
    const float* iw   = (const float*)d_in[2];
    const float* Wm   = (const float*)d_in[3];
    const float* b    = (const float*)d_in[4];
    const float* g    = (const float*)d_in[5];
    const float* be   = (const float*)d_in[6];
    float*       out  = (float*)d_out;

    const size_t featB = (size_t)NN * D * 2;                         // 25.6 MB
    unsigned short* wtp    = (unsigned short*)d_ws;                  // 128 KB
    unsigned short* featb  = (unsigned short*)((char*)d_ws + 131072);
    unsigned short* aggb_w = (unsigned short*)((char*)d_ws + 131072 + featB);

    if (ws_size >= 131072 + 2 * featB) {
        // Full path: slice-major featb, XCD-sliced pool, aggb in d_ws.
        // d_out is WRITE-ONLY (R4 lesson: replay-poison races d_out scratch).
        convert_all<<<dim3(6282), dim3(256), 0, stream>>>(feat, Wm, featb, wtp,
                                                          6250, 1);
        pool_sg<<<dim3(8 * ((NN + 31) / 32)), dim3(256), 0, stream>>>(
            featb, nbr, iw, aggb_w, 256);
        gemm_ln<<<dim3((NN + 63) / 64), dim3(256), 0, stream>>>(
            aggb_w, 256, wtp, b, g, be, out);
    } else if (ws_size >= 131072 + featB) {
        // Proven R0 path: row-major featb, pool_b, aggb aliases d_out.
        unsigned short* aggb = (unsigned short*)d_out;
        convert_all<<<dim3(6282), dim3(256), 0, stream>>>(feat, Wm, featb, wtp,
                                                          6250, 0);
        pool_b<<<dim3(NN / 4), dim3(256), 0, stream>>>(featb, nbr, iw, aggb, 512);
        gemm_ln<<<dim3((NN + 63) / 64), dim3(256), 0, stream>>>(
            aggb, 512, wtp, b, g, be, out);
    } else {
        unsigned short* aggb = (unsigned short*)d_out;
        convert_all<<<dim3(32), dim3(256), 0, stream>>>(feat, Wm, featb, wtp, 0, 0);
        pool_f<<<dim3(NN / 4), dim3(256), 0, stream>>>(feat, nbr, iw, aggb, 512);
        gemm_ln<<<dim3((NN + 63) / 64), dim3(256), 0, stream>>>(
            aggb, 512, wtp, b, g, be, out);
    }
}